// Round 5
// baseline (398.760 us; speedup 1.0000x reference)
//
#include <hip/hip_runtime.h>
#include <hip/hip_fp16.h>
#include <hip/hip_cooperative_groups.h>

namespace cg = cooperative_groups;

#define D_FEAT      128
#define S_BIN       256      // edge slices == coop grid size
#define BUCKET_BITS 7
#define BUCKET_SZ   128      // nodes per bucket
#define NB_MAX      1024     // max buckets (131072 nodes)
#define SORT_CAP    6144     // LDS edge buffer per bucket (mean 2048, max ~2400)
#define CTHREADS    1024     // coop block size (16 waves)
#define CGRID       256      // coop grid (1 block/CU, co-resident)
#define SMEM_INTS   6528     // 26112 B: sort phase is the max user

typedef float f32x4 __attribute__((ext_vector_type(4)));

// ---------------- phase device functions (shared by coop + fallback) ----------------

__device__ void ph_binhist(int* sm, const int* __restrict__ src, const int* __restrict__ dst,
                           int* __restrict__ part2, int n_edges, int nb, int N2,
                           int s, int sl, int tid, int nthr) {
    int* hd = sm; int* hs = sm + NB_MAX;
    for (int i = tid; i < nb; i += nthr) { hd[i] = 0; hs[i] = 0; }
    __syncthreads();
    int beg = s * sl;
    int end = beg + sl; if (end > n_edges) end = n_edges;
    for (int i = beg + tid; i < end; i += nthr) {
        atomicAdd(&hd[dst[i] >> BUCKET_BITS], 1);
        atomicAdd(&hs[src[i] >> BUCKET_BITS], 1);
    }
    __syncthreads();
    for (int b = tid; b < nb; b += nthr) {
        part2[(size_t)b * S_BIN + s] = hd[b];                  // dst half
        part2[(size_t)(N2 + b * S_BIN) + s] = hs[b];           // src half
    }
}

// in-place exclusive scan of one 1024-chunk; chunk total -> bsum[chunk]
__device__ void ph_scan_chunk(int* sm, int* __restrict__ data, int* __restrict__ bsum,
                              int n, int chunk, int tid) {
    int g = chunk * CTHREADS + tid;
    int v = (g < n) ? data[g] : 0;
    sm[tid] = v;
    __syncthreads();
    for (int d = 1; d < CTHREADS; d <<= 1) {
        int x = (tid >= d) ? sm[tid - d] : 0;
        __syncthreads();
        sm[tid] += x;
        __syncthreads();
    }
    if (g < n) data[g] = sm[tid] - v;
    if (tid == CTHREADS - 1) bsum[chunk] = sm[tid];
}

// exclusive scan of chunk sums (nchunks <= 1024), single block
__device__ void ph_scan_top(int* sm, int* __restrict__ bsum, int nchunks, int tid) {
    int v = (tid < nchunks) ? bsum[tid] : 0;
    sm[tid] = v;
    __syncthreads();
    for (int d = 1; d < CTHREADS; d <<= 1) {
        int x = (tid >= d) ? sm[tid - d] : 0;
        __syncthreads();
        sm[tid] += x;
        __syncthreads();
    }
    if (tid < nchunks) bsum[tid] = sm[tid] - v;
}

__device__ void ph_binscatter(int* sm, const int* __restrict__ src, const int* __restrict__ dst,
                              const int* __restrict__ loff, const int* __restrict__ bsum,
                              int* __restrict__ colp, unsigned char* __restrict__ colp_src,
                              int n_edges, int nb, int N2, int s, int sl, int tid, int nthr) {
    int* cd = sm; int* cs = sm + NB_MAX;
    for (int b = tid; b < nb; b += nthr) {
        size_t iD = (size_t)b * S_BIN + s;
        size_t iS = (size_t)N2 + (size_t)b * S_BIN + s;
        cd[b] = loff[iD] + bsum[iD >> 10];
        cs[b] = loff[iS] + bsum[iS >> 10] - n_edges;           // src half rebased
    }
    __syncthreads();
    int beg = s * sl;
    int end = beg + sl; if (end > n_edges) end = n_edges;
    for (int i = beg + tid; i < end; i += nthr) {
        int d = dst[i], sv = src[i];
        int pD = atomicAdd(&cd[d >> BUCKET_BITS], 1);          // native LDS int atomic
        colp[pD] = sv | ((d & (BUCKET_SZ - 1)) << 20);
        int pS = atomicAdd(&cs[sv >> BUCKET_BITS], 1);
        colp_src[pS] = (unsigned char)(sv & (BUCKET_SZ - 1));
    }
    __syncthreads();
}

// unit u in [0,nb): in-bucket counting sort -> node_off; u in [nb,2nb): out-degree -> norm_l
__device__ void ph_sortunit(int* sm, int* __restrict__ colp,
                            const unsigned char* __restrict__ colp_src,
                            const int* __restrict__ loff, const int* __restrict__ bsum,
                            int* __restrict__ node_off, float* __restrict__ norm_l,
                            int n_nodes, int n_edges, int nb, int N2, int u, int tid, int nthr) {
    int* buf = sm;
    int* cnt = sm + SORT_CAP;
    int* sa  = sm + SORT_CAP + BUCKET_SZ;
    int* sb  = sm + SORT_CAP + 2 * BUCKET_SZ;
    __syncthreads();                                           // LDS reuse fence

    if (u >= nb) {
        int b = u - nb;                                        // ---- countsrc ----
        size_t iA = (size_t)N2 + (size_t)b * S_BIN;
        int beg = loff[iA] + bsum[iA >> 10] - n_edges;
        int end;
        if (b + 1 < nb) {
            size_t iB = (size_t)N2 + (size_t)(b + 1) * S_BIN;
            end = loff[iB] + bsum[iB >> 10] - n_edges;
        } else end = n_edges;
        if (tid < BUCKET_SZ) cnt[tid] = 0;
        __syncthreads();
        for (int i = beg + tid; i < end; i += nthr)
            atomicAdd(&cnt[colp_src[i]], 1);
        __syncthreads();
        int node0 = b << BUCKET_BITS;
        int bn = n_nodes - node0; if (bn > BUCKET_SZ) bn = BUCKET_SZ;
        if (tid < bn) {
            int c = cnt[tid]; if (c < 1) c = 1;
            norm_l[node0 + tid] = rsqrtf((float)c);
        }
        __syncthreads();
        return;
    }

    int b = u;                                                 // ---- sort ----
    size_t iA = (size_t)b * S_BIN;
    int beg = loff[iA] + bsum[iA >> 10];
    int end;
    if (b + 1 < nb) {
        size_t iB = (size_t)(b + 1) * S_BIN;
        end = loff[iB] + bsum[iB >> 10];
    } else end = n_edges;
    int m = end - beg;                                         // ~2048 << SORT_CAP
    if (tid < BUCKET_SZ) cnt[tid] = 0;
    __syncthreads();
    for (int i = tid; i < m; i += nthr) {
        int v = colp[beg + i];
        if (i < SORT_CAP) buf[i] = v;
        atomicAdd(&cnt[(v >> 20) & (BUCKET_SZ - 1)], 1);
    }
    __syncthreads();
    int* rp = sa; int* wp = sb;                                // inclusive scan ping-pong
    if (tid < BUCKET_SZ) sa[tid] = cnt[tid];
    __syncthreads();
    for (int d = 1; d < BUCKET_SZ; d <<= 1) {
        if (tid < BUCKET_SZ) wp[tid] = rp[tid] + (tid >= d ? rp[tid - d] : 0);
        __syncthreads();
        int* t = rp; rp = wp; wp = t;
    }
    int node0 = b << BUCKET_BITS;
    int bn = n_nodes - node0; if (bn > BUCKET_SZ) bn = BUCKET_SZ;
    if (tid < BUCKET_SZ) {
        int ex = rp[tid] - cnt[tid];                           // exclusive
        wp[tid] = ex;                                          // cursors
        if (tid < bn) node_off[node0 + tid] = beg + ex;
    }
    if (b == nb - 1 && tid == 0) node_off[n_nodes] = end;
    __syncthreads();
    int mm = m < SORT_CAP ? m : SORT_CAP;
    for (int i = tid; i < mm; i += nthr) {
        int v = buf[i];
        int p = atomicAdd(&wp[(v >> 20) & (BUCKET_SZ - 1)], 1);
        colp[beg + p] = v & 0xFFFFF;                           // src only (17 bits)
    }
    __syncthreads();
}

__device__ void ph_convert(const float* __restrict__ feat, const float* __restrict__ norm_l,
                           __half* __restrict__ feat16, int total, int gid, int stride) {
    for (int t = gid; t < total; t += stride) {
        float nl = norm_l[t >> 4];                             // 16 threads per 128-elem row
        const f32x4* fp = (const f32x4*)feat + (size_t)t * 2;
        f32x4 a = __builtin_nontemporal_load(fp);
        f32x4 b = __builtin_nontemporal_load(fp + 1);
        __half2 h0 = __floats2half2_rn(a.x * nl, a.y * nl);
        __half2 h1 = __floats2half2_rn(a.z * nl, a.w * nl);
        __half2 h2 = __floats2half2_rn(b.x * nl, b.y * nl);
        __half2 h3 = __floats2half2_rn(b.z * nl, b.w * nl);
        uint4 o;
        o.x = *(unsigned int*)&h0; o.y = *(unsigned int*)&h1;
        o.z = *(unsigned int*)&h2; o.w = *(unsigned int*)&h3;
        ((uint4*)feat16)[t] = o;
    }
}

// ---------------- fused cooperative preprocessing (1 launch) ----------------

__global__ __launch_bounds__(CTHREADS) void coop_preproc(
        const int* __restrict__ src, const int* __restrict__ dst,
        const float* __restrict__ feat, int* __restrict__ part2, int* __restrict__ bsum,
        int* __restrict__ colp, unsigned char* __restrict__ colp_src,
        int* __restrict__ node_off, float* __restrict__ norm_l, __half* __restrict__ feat16,
        int n_nodes, int n_edges, int nb, int N2, int sl) {
    __shared__ int sm[SMEM_INTS];
    cg::grid_group grid = cg::this_grid();
    int tid = threadIdx.x, blk = blockIdx.x;
    int NSCAN = 2 * N2;
    int nch = (NSCAN + CTHREADS - 1) / CTHREADS;               // 391

    ph_binhist(sm, src, dst, part2, n_edges, nb, N2, blk, sl, tid, CTHREADS);
    grid.sync();
    for (int c = blk; c < nch; c += CGRID) {
        __syncthreads();
        ph_scan_chunk(sm, part2, bsum, NSCAN, c, tid);
    }
    grid.sync();
    if (blk == 0) ph_scan_top(sm, bsum, nch, tid);
    grid.sync();
    ph_binscatter(sm, src, dst, part2, bsum, colp, colp_src, n_edges, nb, N2, blk, sl,
                  tid, CTHREADS);
    grid.sync();
    for (int u = blk; u < 2 * nb; u += CGRID)
        ph_sortunit(sm, colp, colp_src, part2, bsum, node_off, norm_l,
                    n_nodes, n_edges, nb, N2, u, tid, CTHREADS);
    grid.sync();
    ph_convert(feat, norm_l, feat16, n_nodes * (D_FEAT / 8),
               blk * CTHREADS + tid, CGRID * CTHREADS);
}

// ---------------- fallback wrappers (if cooperative launch is unavailable) ----------------

__global__ __launch_bounds__(CTHREADS) void k_binhist(const int* src, const int* dst, int* part2,
        int n_edges, int nb, int N2, int sl) {
    __shared__ int sm[SMEM_INTS];
    ph_binhist(sm, src, dst, part2, n_edges, nb, N2, blockIdx.x, sl, threadIdx.x, CTHREADS);
}
__global__ __launch_bounds__(CTHREADS) void k_scan1(int* data, int* bsum, int n) {
    __shared__ int sm[SMEM_INTS];
    ph_scan_chunk(sm, data, bsum, n, blockIdx.x, threadIdx.x);
}
__global__ __launch_bounds__(CTHREADS) void k_scan2(int* bsum, int nchunks) {
    __shared__ int sm[SMEM_INTS];
    ph_scan_top(sm, bsum, nchunks, threadIdx.x);
}
__global__ __launch_bounds__(CTHREADS) void k_binscatter(const int* src, const int* dst,
        const int* loff, const int* bsum, int* colp, unsigned char* colp_src,
        int n_edges, int nb, int N2, int sl) {
    __shared__ int sm[SMEM_INTS];
    ph_binscatter(sm, src, dst, loff, bsum, colp, colp_src, n_edges, nb, N2, blockIdx.x, sl,
                  threadIdx.x, CTHREADS);
}
__global__ __launch_bounds__(CTHREADS) void k_sortcount(int* colp, const unsigned char* colp_src,
        const int* loff, const int* bsum, int* node_off, float* norm_l,
        int n_nodes, int n_edges, int nb, int N2) {
    __shared__ int sm[SMEM_INTS];
    ph_sortunit(sm, colp, colp_src, loff, bsum, node_off, norm_l, n_nodes, n_edges, nb, N2,
                blockIdx.x, threadIdx.x, CTHREADS);
}
__global__ __launch_bounds__(CTHREADS) void k_convert(const float* feat, const float* norm_l,
        __half* feat16, int total) {
    ph_convert(feat, norm_l, feat16, total,
               blockIdx.x * blockDim.x + threadIdx.x, gridDim.x * blockDim.x);
}

// ---------------- pull: 4 edges/vmem, branchless loads for deep MLP ----------------
__global__ __launch_bounds__(256) void pull_csr_kernel(
        const __half* __restrict__ feat16, const int* __restrict__ col,
        const int* __restrict__ node_off, float* __restrict__ out,
        int n_nodes, int n_edges) {
    int lane = threadIdx.x & 63;
    int wid  = (int)(((long long)blockIdx.x * blockDim.x + threadIdx.x) >> 6);
    int h  = lane >> 5;            // node half
    int g  = (lane >> 4) & 1;      // edge subgroup within half
    int dl = lane & 15;            // dim lane (16 B of the row)
    int node = wid * 2 + h;
    bool nvalid = node < n_nodes;
    int nsafe = nvalid ? node : n_nodes - 1;
    int s = node_off[nsafe];
    int e = nvalid ? node_off[nsafe + 1] : s;
    int m = e - s;
    int om = __shfl_xor(m, 32, 64);                            // other half's count
    int mm = m > om ? m : om;                                  // wave-max

    float a0=0.f,a1=0.f,a2=0.f,a3=0.f,a4=0.f,a5=0.f,a6=0.f,a7=0.f;
    const uint4* rowb = (const uint4*)feat16;

    for (int base = 0; base < mm; base += 32) {
        int remh = m - base;
        int ci = lane & 31;
        if (ci >= remh) ci = (remh > 0) ? remh - 1 : 0;        // clamp to a valid edge
        int cidx = s + base + ci;
        if (cidx >= n_edges) cidx = n_edges - 1;               // empty-node guard
        int cv = col[cidx];                                    // coalesced chunk
        int lim = mm - base; if (lim > 32) lim = 32;
        for (int k = 0; k < lim; k += 2) {
            int srcl = (lane & 32) + k + g;
            int idx = __shfl(cv, srcl, 64);                    // broadcast within half
            uint4 hv = rowb[((size_t)(unsigned)idx << 4) + dl]; // unconditional: valid row
            float wm = (base + k + g < m) ? 1.f : 0.f;         // mask accumulate only
            float2 f;
            f = __half22float2(*(__half2*)&hv.x); a0 += wm * f.x; a1 += wm * f.y;
            f = __half22float2(*(__half2*)&hv.y); a2 += wm * f.x; a3 += wm * f.y;
            f = __half22float2(*(__half2*)&hv.z); a4 += wm * f.x; a5 += wm * f.y;
            f = __half22float2(*(__half2*)&hv.w); a6 += wm * f.x; a7 += wm * f.y;
        }
    }

    a0 += __shfl_xor(a0, 16, 64); a1 += __shfl_xor(a1, 16, 64);
    a2 += __shfl_xor(a2, 16, 64); a3 += __shfl_xor(a3, 16, 64);
    a4 += __shfl_xor(a4, 16, 64); a5 += __shfl_xor(a5, 16, 64);
    a6 += __shfl_xor(a6, 16, 64); a7 += __shfl_xor(a7, 16, 64);

    if (nvalid && g == 0) {
        int c = m < 1 ? 1 : m;
        float nr = rsqrtf((float)c);
        f32x4 o0 = {a0 * nr, a1 * nr, a2 * nr, a3 * nr};
        f32x4 o1 = {a4 * nr, a5 * nr, a6 * nr, a7 * nr};
        f32x4* op = (f32x4*)(out + (size_t)node * D_FEAT) + dl * 2;
        __builtin_nontemporal_store(o0, op);
        __builtin_nontemporal_store(o1, op + 1);
    }
}

extern "C" void kernel_launch(void* const* d_in, const int* in_sizes, int n_in,
                              void* d_out, int out_size, void* d_ws, size_t ws_size,
                              hipStream_t stream) {
    const float* feat = (const float*)d_in[0];
    const int*   src  = (const int*)d_in[1];
    const int*   dst  = (const int*)d_in[2];
    float* out = (float*)d_out;

    int n_nodes = in_sizes[0] / D_FEAT;                       // 100000
    int n_edges = in_sizes[1];                                // 1600000
    int nb = (n_nodes + BUCKET_SZ - 1) / BUCKET_SZ;           // 782
    int N2 = nb * S_BIN;                                      // 200192 per half
    int NSCAN = 2 * N2;                                       // 400384
    int sl = (n_edges + S_BIN - 1) / S_BIN;                   // 6250

    // ws (~36 MB): node_off norm_l part2(in-place scan) bsum colp colp_src feat16
    auto alignup = [](size_t x) { return (x + 255) & ~(size_t)255; };
    char* p = (char*)d_ws;
    int*    node_off = (int*)p;            p += alignup((size_t)(n_nodes + 1) * 4);
    float*  norm_l   = (float*)p;          p += alignup((size_t)n_nodes * 4);
    int*    part2    = (int*)p;            p += alignup((size_t)NSCAN * 4);
    int*    bsum     = (int*)p;            p += alignup((size_t)CTHREADS * 4);
    int*    colp     = (int*)p;            p += alignup((size_t)n_edges * 4);
    unsigned char* colp_src = (unsigned char*)p; p += alignup((size_t)n_edges);
    __half* feat16   = (__half*)p;

    // --- one cooperative launch fuses the 6 preprocessing phases ---
    void* cargs[] = { (void*)&src, (void*)&dst, (void*)&feat, (void*)&part2, (void*)&bsum,
                      (void*)&colp, (void*)&colp_src, (void*)&node_off, (void*)&norm_l,
                      (void*)&feat16, (void*)&n_nodes, (void*)&n_edges, (void*)&nb,
                      (void*)&N2, (void*)&sl };
    hipError_t cerr = hipLaunchCooperativeKernel((const void*)coop_preproc,
                                                 dim3(CGRID), dim3(CTHREADS),
                                                 cargs, 0, stream);
    if (cerr != hipSuccess) {
        // fallback: same phases as separate launches
        int nch = (NSCAN + CTHREADS - 1) / CTHREADS;
        k_binhist<<<S_BIN, CTHREADS, 0, stream>>>(src, dst, part2, n_edges, nb, N2, sl);
        k_scan1<<<nch, CTHREADS, 0, stream>>>(part2, bsum, NSCAN);
        k_scan2<<<1, CTHREADS, 0, stream>>>(bsum, nch);
        k_binscatter<<<S_BIN, CTHREADS, 0, stream>>>(src, dst, part2, bsum, colp, colp_src,
                                                     n_edges, nb, N2, sl);
        k_sortcount<<<2 * nb, CTHREADS, 0, stream>>>(colp, colp_src, part2, bsum, node_off,
                                                     norm_l, n_nodes, n_edges, nb, N2);
        int total16 = n_nodes * (D_FEAT / 8);
        k_convert<<<(total16 + CTHREADS - 1) / CTHREADS, CTHREADS, 0, stream>>>(
            feat, norm_l, feat16, total16);
    }

    // --- pull: one wave per 2 nodes, 4 edges per vmem instruction ---
    {
        long long waves = ((long long)n_nodes + 1) / 2;
        long long total = waves * 64;
        pull_csr_kernel<<<(int)((total + 255) / 256), 256, 0, stream>>>(feat16, colp, node_off,
                                                                        out, n_nodes, n_edges);
    }
}

// Round 6
// 227.554 us; speedup vs baseline: 1.7524x; 1.7524x over previous
//
#include <hip/hip_runtime.h>
#include <hip/hip_fp16.h>

#define D_FEAT      128
#define S_BIN       256      // edge slices (cursor granularity; keeps scatter runs ~8)
#define BUCKET_BITS 7
#define BUCKET_SZ   128      // nodes per bucket
#define NB_MAX      1024     // max buckets (131072 nodes)
#define SORT_CAP    6144     // LDS edge buffer per bucket (mean 2048, max ~2300)
#define BIGB        1024     // fat block for latency-bound LDS-atomic kernels

typedef float f32x4 __attribute__((ext_vector_type(4)));

// --- 1. fused per-slice bucket histograms of dst AND src (LDS only, no global atomics).
//     1024 threads/block: 16 waves/CU to hide LDS-atomic + load latency. ---
__global__ __launch_bounds__(BIGB) void binhist2_kernel(
        const int* __restrict__ src, const int* __restrict__ dst,
        int* __restrict__ part2, int n_edges, int nb, int N2, int slice_len) {
    __shared__ int hd[NB_MAX];
    __shared__ int hs[NB_MAX];
    int s = blockIdx.x, tid = threadIdx.x;
    for (int i = tid; i < nb; i += BIGB) { hd[i] = 0; hs[i] = 0; }
    __syncthreads();
    int beg = s * slice_len;
    int end = beg + slice_len; if (end > n_edges) end = n_edges;
    for (int i = beg + tid; i < end; i += BIGB) {
        atomicAdd(&hd[dst[i] >> BUCKET_BITS], 1);
        atomicAdd(&hs[src[i] >> BUCKET_BITS], 1);
    }
    __syncthreads();
    for (int b = tid; b < nb; b += BIGB) {
        part2[(size_t)b * S_BIN + s] = hd[b];                  // dst half
        part2[(size_t)(N2 + b * S_BIN) + s] = hs[b];           // src half
    }
}

// --- 2a. in-place exclusive scan per 1024-chunk, wave-shuffle (2 barriers);
//         chunk total -> bsum[chunk]; consumers add bsum[idx>>10]. ---
__global__ __launch_bounds__(BIGB) void scan1_kernel(int* __restrict__ data,
        int* __restrict__ bsum, int n) {
    __shared__ int wsum[16];
    int tid = threadIdx.x;
    int g = blockIdx.x * BIGB + tid;
    int lane = tid & 63, w = tid >> 6;
    int v = (g < n) ? data[g] : 0;
    int incl = v;
    #pragma unroll
    for (int d = 1; d < 64; d <<= 1) {
        int x = __shfl_up(incl, d, 64);
        if (lane >= d) incl += x;
    }
    if (lane == 63) wsum[w] = incl;
    __syncthreads();
    if (w == 0) {
        int sv = (lane < 16) ? wsum[lane] : 0;
        #pragma unroll
        for (int d = 1; d < 16; d <<= 1) {
            int x = __shfl_up(sv, d, 64);
            if (lane >= d) sv += x;
        }
        if (lane < 16) wsum[lane] = sv;                        // inclusive wave prefix
    }
    __syncthreads();
    int wpre = (w > 0) ? wsum[w - 1] : 0;
    if (g < n) data[g] = wpre + incl - v;                      // exclusive
    if (tid == BIGB - 1) bsum[blockIdx.x] = wpre + incl;       // grand total
}

// --- 2b. exclusive scan of chunk sums (<=1024), single block, wave-shuffle ---
__global__ __launch_bounds__(BIGB) void scan2_kernel(int* __restrict__ bsum, int nchunks) {
    __shared__ int wsum[16];
    int tid = threadIdx.x;
    int lane = tid & 63, w = tid >> 6;
    int v = (tid < nchunks) ? bsum[tid] : 0;
    int incl = v;
    #pragma unroll
    for (int d = 1; d < 64; d <<= 1) {
        int x = __shfl_up(incl, d, 64);
        if (lane >= d) incl += x;
    }
    if (lane == 63) wsum[w] = incl;
    __syncthreads();
    if (w == 0) {
        int sv = (lane < 16) ? wsum[lane] : 0;
        #pragma unroll
        for (int d = 1; d < 16; d <<= 1) {
            int x = __shfl_up(sv, d, 64);
            if (lane >= d) sv += x;
        }
        if (lane < 16) wsum[lane] = sv;
    }
    __syncthreads();
    int wpre = (w > 0) ? wsum[w - 1] : 0;
    if (tid < nchunks) bsum[tid] = wpre + incl - v;            // exclusive
}

// --- 3. scatter edges into bucket-grouped streams via LDS cursors (no global atomics).
//     colp: dst-bucketed, packs src | (dst&127)<<20.  colp_src: src-bucketed, src&127. ---
__global__ __launch_bounds__(BIGB) void binscatter2_kernel(
        const int* __restrict__ src, const int* __restrict__ dst,
        const int* __restrict__ loff, const int* __restrict__ bsum,
        int* __restrict__ colp, unsigned char* __restrict__ colp_src,
        int n_edges, int nb, int N2, int slice_len) {
    __shared__ int cd[NB_MAX];
    __shared__ int cs[NB_MAX];
    int s = blockIdx.x, tid = threadIdx.x;
    for (int b = tid; b < nb; b += BIGB) {
        size_t iD = (size_t)b * S_BIN + s;
        size_t iS = (size_t)N2 + (size_t)b * S_BIN + s;
        cd[b] = loff[iD] + bsum[iD >> 10];
        cs[b] = loff[iS] + bsum[iS >> 10] - n_edges;           // src half rebased
    }
    __syncthreads();
    int beg = s * slice_len;
    int end = beg + slice_len; if (end > n_edges) end = n_edges;
    for (int i = beg + tid; i < end; i += BIGB) {
        int d = dst[i], sv = src[i];
        int pD = atomicAdd(&cd[d >> BUCKET_BITS], 1);          // native LDS int atomic
        colp[pD] = sv | ((d & (BUCKET_SZ - 1)) << 20);
        int pS = atomicAdd(&cs[sv >> BUCKET_BITS], 1);
        colp_src[pS] = (unsigned char)(sv & (BUCKET_SZ - 1));
    }
}

// --- 4. merged: blocks [0,nb) in-bucket counting sort -> per-node CSR + node_off;
//        blocks [nb,2nb) out-degree count from colp_src -> norm_l.  (round-4 proven) ---
__global__ __launch_bounds__(256) void sortcount_kernel(
        int* __restrict__ colp, const unsigned char* __restrict__ colp_src,
        const int* __restrict__ loff, const int* __restrict__ bsum,
        int* __restrict__ node_off, float* __restrict__ norm_l,
        int n_nodes, int n_edges, int nb, int N2) {
    __shared__ int buf[SORT_CAP];
    __shared__ int cnt[BUCKET_SZ];
    __shared__ int sa[BUCKET_SZ];
    __shared__ int sb[BUCKET_SZ];
    int tid = threadIdx.x;

    if ((int)blockIdx.x >= nb) {
        int b = blockIdx.x - nb;                               // ---- countsrc ----
        size_t iA = (size_t)N2 + (size_t)b * S_BIN;
        int beg = loff[iA] + bsum[iA >> 10] - n_edges;
        int end;
        if (b + 1 < nb) {
            size_t iB = (size_t)N2 + (size_t)(b + 1) * S_BIN;
            end = loff[iB] + bsum[iB >> 10] - n_edges;
        } else end = n_edges;
        if (tid < BUCKET_SZ) cnt[tid] = 0;
        __syncthreads();
        for (int i = beg + tid; i < end; i += blockDim.x)
            atomicAdd(&cnt[colp_src[i]], 1);
        __syncthreads();
        int node0 = b << BUCKET_BITS;
        int bn = n_nodes - node0; if (bn > BUCKET_SZ) bn = BUCKET_SZ;
        if (tid < bn) {
            int c = cnt[tid]; if (c < 1) c = 1;
            norm_l[node0 + tid] = rsqrtf((float)c);
        }
        return;
    }

    int b = blockIdx.x;                                        // ---- sort ----
    size_t iA = (size_t)b * S_BIN;
    int beg = loff[iA] + bsum[iA >> 10];
    int end;
    if (b + 1 < nb) {
        size_t iB = (size_t)(b + 1) * S_BIN;
        end = loff[iB] + bsum[iB >> 10];
    } else end = n_edges;
    int m = end - beg;                                         // ~2048 << SORT_CAP
    if (tid < BUCKET_SZ) cnt[tid] = 0;
    __syncthreads();
    for (int i = tid; i < m; i += blockDim.x) {
        int v = colp[beg + i];
        if (i < SORT_CAP) buf[i] = v;
        atomicAdd(&cnt[(v >> 20) & (BUCKET_SZ - 1)], 1);
    }
    __syncthreads();
    int* rp = sa; int* wp = sb;                                // inclusive scan ping-pong
    if (tid < BUCKET_SZ) sa[tid] = cnt[tid];
    __syncthreads();
    for (int d = 1; d < BUCKET_SZ; d <<= 1) {
        if (tid < BUCKET_SZ) wp[tid] = rp[tid] + (tid >= d ? rp[tid - d] : 0);
        __syncthreads();
        int* t = rp; rp = wp; wp = t;
    }
    int node0 = b << BUCKET_BITS;
    int bn = n_nodes - node0; if (bn > BUCKET_SZ) bn = BUCKET_SZ;
    if (tid < BUCKET_SZ) {
        int ex = rp[tid] - cnt[tid];                           // exclusive
        wp[tid] = ex;                                          // cursors
        if (tid < bn) node_off[node0 + tid] = beg + ex;
    }
    if (b == nb - 1 && tid == 0) node_off[n_nodes] = end;
    __syncthreads();
    int mm = m < SORT_CAP ? m : SORT_CAP;
    for (int i = tid; i < mm; i += blockDim.x) {
        int v = buf[i];
        int p = atomicAdd(&wp[(v >> 20) & (BUCKET_SZ - 1)], 1);
        colp[beg + p] = v & 0xFFFFF;                           // src only (17 bits)
    }
}

// --- 5. fp16 pre-scaled features: feat16 = (half)(feat * norm_l[row]); NT feat loads ---
__global__ void convert_kernel(const float* __restrict__ feat, const float* __restrict__ norm_l,
                               __half* __restrict__ feat16, int n_nodes) {
    int t = blockIdx.x * blockDim.x + threadIdx.x;
    int total = n_nodes * (D_FEAT / 8);
    if (t >= total) return;
    float nl = norm_l[t >> 4];                                 // 16 threads per 128-elem row
    const f32x4* fp = (const f32x4*)feat + (size_t)t * 2;
    f32x4 a = __builtin_nontemporal_load(fp);
    f32x4 b = __builtin_nontemporal_load(fp + 1);
    __half2 h0 = __floats2half2_rn(a.x * nl, a.y * nl);
    __half2 h1 = __floats2half2_rn(a.z * nl, a.w * nl);
    __half2 h2 = __floats2half2_rn(b.x * nl, b.y * nl);
    __half2 h3 = __floats2half2_rn(b.z * nl, b.w * nl);
    uint4 o;
    o.x = *(unsigned int*)&h0; o.y = *(unsigned int*)&h1;
    o.z = *(unsigned int*)&h2; o.w = *(unsigned int*)&h3;
    ((uint4*)feat16)[t] = o;
}

// --- 6. CSR pull (round-4 verbatim, 61 us measured): 4 edges per vmem instruction;
//     wave = 2 nodes (32-lane halves); 16-lane subgroup loads a 256 B row as uint4.
//     Branchless loads (clamped), masked accumulate, NT dwordx4 stores. Zero atomics. ---
__global__ __launch_bounds__(256) void pull_csr_kernel(
        const __half* __restrict__ feat16, const int* __restrict__ col,
        const int* __restrict__ node_off, float* __restrict__ out,
        int n_nodes, int n_edges) {
    int lane = threadIdx.x & 63;
    int wid  = (int)(((long long)blockIdx.x * blockDim.x + threadIdx.x) >> 6);
    int h  = lane >> 5;            // node half
    int g  = (lane >> 4) & 1;      // edge subgroup within half
    int dl = lane & 15;            // dim lane (16 B of the row)
    int node = wid * 2 + h;
    bool nvalid = node < n_nodes;
    int nsafe = nvalid ? node : n_nodes - 1;
    int s = node_off[nsafe];
    int e = nvalid ? node_off[nsafe + 1] : s;
    int m = e - s;
    int om = __shfl_xor(m, 32, 64);                            // other half's count
    int mm = m > om ? m : om;                                  // wave-max

    float a0=0.f,a1=0.f,a2=0.f,a3=0.f,a4=0.f,a5=0.f,a6=0.f,a7=0.f;
    const uint4* rowb = (const uint4*)feat16;

    for (int base = 0; base < mm; base += 32) {
        int remh = m - base;
        int ci = lane & 31;
        if (ci >= remh) ci = (remh > 0) ? remh - 1 : 0;        // clamp to a valid edge
        int cidx = s + base + ci;
        if (cidx >= n_edges) cidx = n_edges - 1;               // empty-node guard
        int cv = col[cidx];                                    // coalesced chunk
        int lim = mm - base; if (lim > 32) lim = 32;
        for (int k = 0; k < lim; k += 2) {
            int srcl = (lane & 32) + k + g;
            int idx = __shfl(cv, srcl, 64);                    // broadcast within half
            uint4 hv = rowb[((size_t)(unsigned)idx << 4) + dl]; // unconditional: valid row
            float wm = (base + k + g < m) ? 1.f : 0.f;         // mask accumulate only
            float2 f;
            f = __half22float2(*(__half2*)&hv.x); a0 += wm * f.x; a1 += wm * f.y;
            f = __half22float2(*(__half2*)&hv.y); a2 += wm * f.x; a3 += wm * f.y;
            f = __half22float2(*(__half2*)&hv.z); a4 += wm * f.x; a5 += wm * f.y;
            f = __half22float2(*(__half2*)&hv.w); a6 += wm * f.x; a7 += wm * f.y;
        }
    }

    a0 += __shfl_xor(a0, 16, 64); a1 += __shfl_xor(a1, 16, 64);
    a2 += __shfl_xor(a2, 16, 64); a3 += __shfl_xor(a3, 16, 64);
    a4 += __shfl_xor(a4, 16, 64); a5 += __shfl_xor(a5, 16, 64);
    a6 += __shfl_xor(a6, 16, 64); a7 += __shfl_xor(a7, 16, 64);

    if (nvalid && g == 0) {
        int c = m < 1 ? 1 : m;
        float nr = rsqrtf((float)c);
        f32x4 o0 = {a0 * nr, a1 * nr, a2 * nr, a3 * nr};
        f32x4 o1 = {a4 * nr, a5 * nr, a6 * nr, a7 * nr};
        f32x4* op = (f32x4*)(out + (size_t)node * D_FEAT) + dl * 2;
        __builtin_nontemporal_store(o0, op);
        __builtin_nontemporal_store(o1, op + 1);
    }
}

extern "C" void kernel_launch(void* const* d_in, const int* in_sizes, int n_in,
                              void* d_out, int out_size, void* d_ws, size_t ws_size,
                              hipStream_t stream) {
    const float* feat = (const float*)d_in[0];
    const int*   src  = (const int*)d_in[1];
    const int*   dst  = (const int*)d_in[2];
    float* out = (float*)d_out;

    int n_nodes = in_sizes[0] / D_FEAT;                       // 100000
    int n_edges = in_sizes[1];                                // 1600000
    int nb = (n_nodes + BUCKET_SZ - 1) / BUCKET_SZ;           // 782
    int N2 = nb * S_BIN;                                      // 200192 per half
    int NSCAN = 2 * N2;                                       // 400384
    int sl = (n_edges + S_BIN - 1) / S_BIN;                   // 6250

    // ws (~36 MB): node_off norm_l part2(in-place scan) bsum colp colp_src feat16
    auto alignup = [](size_t x) { return (x + 255) & ~(size_t)255; };
    char* p = (char*)d_ws;
    int*    node_off = (int*)p;            p += alignup((size_t)(n_nodes + 1) * 4);
    float*  norm_l   = (float*)p;          p += alignup((size_t)n_nodes * 4);
    int*    part2    = (int*)p;            p += alignup((size_t)NSCAN * 4);
    int*    bsum     = (int*)p;            p += alignup((size_t)BIGB * 4);
    int*    colp     = (int*)p;            p += alignup((size_t)n_edges * 4);
    unsigned char* colp_src = (unsigned char*)p; p += alignup((size_t)n_edges);
    __half* feat16   = (__half*)p;

    // 1. fused bucket histograms (dst + src) — fat blocks for latency hiding
    binhist2_kernel<<<S_BIN, BIGB, 0, stream>>>(src, dst, part2, n_edges, nb, N2, sl);

    // 2. two-level exclusive scan (in place, wave-shuffle); consumers add bsum themselves
    {
        int nch = (NSCAN + BIGB - 1) / BIGB;                  // 391
        scan1_kernel<<<nch, BIGB, 0, stream>>>(part2, bsum, NSCAN);
        scan2_kernel<<<1, BIGB, 0, stream>>>(bsum, nch);
    }

    // 3. bucket-grouped edge streams (LDS cursors) — fat blocks
    binscatter2_kernel<<<S_BIN, BIGB, 0, stream>>>(src, dst, part2, bsum, colp, colp_src,
                                                   n_edges, nb, N2, sl);

    // 4. merged in-bucket counting sort (-> node_off) + out-degree count (-> norm_l)
    sortcount_kernel<<<2 * nb, 256, 0, stream>>>(colp, colp_src, part2, bsum, node_off,
                                                 norm_l, n_nodes, n_edges, nb, N2);

    // 5. fp16 pre-scaled features
    {
        int total = n_nodes * (D_FEAT / 8);
        convert_kernel<<<(total + 255) / 256, 256, 0, stream>>>(feat, norm_l, feat16, n_nodes);
    }

    // 6. pull: one wave per 2 nodes, 4 edges per vmem instruction
    {
        long long waves = ((long long)n_nodes + 1) / 2;
        long long total = waves * 64;
        pull_csr_kernel<<<(int)((total + 255) / 256), 256, 0, stream>>>(feat16, colp, node_off,
                                                                        out, n_nodes, n_edges);
    }
}